// Round 1
// baseline (825.147 us; speedup 1.0000x reference)
//
#include <hip/hip_runtime.h>
#include <stdint.h>

typedef unsigned int uint;
typedef unsigned short ushort;

__device__ __forceinline__ ushort f2bf(float f) {
    uint u = __float_as_uint(f);
    return (ushort)((u + 0x7fffu + ((u >> 16) & 1u)) >> 16);   // RNE
}
__device__ __forceinline__ float bf2f(ushort h) {
    return __uint_as_float(((uint)h) << 16);
}

// ---- CSR build ------------------------------------------------------------

__global__ void k_zero2(int* __restrict__ a, int* __restrict__ b, int n) {
    int i = blockIdx.x * blockDim.x + threadIdx.x;
    if (i < n) { a[i] = 0; b[i] = 0; }
}

__global__ void k_hist(const int* __restrict__ rows, int* __restrict__ counts, int nnz) {
    int i = blockIdx.x * blockDim.x + threadIdx.x;
    if (i < nnz) atomicAdd(&counts[rows[i]], 1);
}

// chunk = 1024 elements per block (256 thr * 4)
__global__ void k_scan_part(const int* __restrict__ counts, int* __restrict__ partials, int N) {
    int t = threadIdx.x;
    int base = blockIdx.x * 1024 + t * 4;
    int s = 0;
#pragma unroll
    for (int j = 0; j < 4; j++) { int idx = base + j; if (idx < N) s += counts[idx]; }
#pragma unroll
    for (int off = 32; off > 0; off >>= 1) s += __shfl_xor(s, off);
    __shared__ int wsum[4];
    int lane = t & 63, wv = t >> 6;
    if (lane == 0) wsum[wv] = s;
    __syncthreads();
    if (t == 0) partials[blockIdx.x] = wsum[0] + wsum[1] + wsum[2] + wsum[3];
}

__global__ void k_scan_root(int* partials, int P) {
    int t = threadIdx.x;
    int v = (t < P) ? partials[t] : 0;
    int lane = t & 63, wv = t >> 6;
    int inc = v;
#pragma unroll
    for (int off = 1; off < 64; off <<= 1) { int o = __shfl_up(inc, off); if (lane >= off) inc += o; }
    __shared__ int wtot[4];
    if (lane == 63) wtot[wv] = inc;
    __syncthreads();
    int woff = 0;
    for (int i = 0; i < wv; i++) woff += wtot[i];
    int excl = inc - v + woff;
    if (t < P) partials[t] = excl;
}

__global__ void k_scan_final(const int* __restrict__ counts, const int* __restrict__ partials,
                             int* __restrict__ offsets, int N) {
    int t = threadIdx.x, b = blockIdx.x;
    int base = b * 1024 + t * 4;
    int v[4]; int tsum = 0;
#pragma unroll
    for (int j = 0; j < 4; j++) { int idx = base + j; v[j] = (idx < N) ? counts[idx] : 0; tsum += v[j]; }
    int lane = t & 63, wv = t >> 6;
    int inc = tsum;
#pragma unroll
    for (int off = 1; off < 64; off <<= 1) { int o = __shfl_up(inc, off); if (lane >= off) inc += o; }
    __shared__ int wtot[4];
    if (lane == 63) wtot[wv] = inc;
    __syncthreads();
    int woff = 0;
    for (int i = 0; i < wv; i++) woff += wtot[i];
    int run = partials[b] + woff + inc - tsum;
#pragma unroll
    for (int j = 0; j < 4; j++) { int idx = base + j; if (idx < N) offsets[idx] = run; run += v[j]; }
}

__global__ void k_scatter(const int* __restrict__ rows, const int* __restrict__ cols,
                          const float* __restrict__ vals, const int* __restrict__ offsets,
                          int* __restrict__ cursor, int* __restrict__ col_s,
                          float* __restrict__ val_s, int nnz) {
    int i = blockIdx.x * blockDim.x + threadIdx.x;
    if (i < nnz) {
        int r = rows[i];
        int p = offsets[r] + atomicAdd(&cursor[r], 1);
        col_s[p] = cols[i];
        val_s[p] = vals[i];
    }
}

// ---- x -> bf16 ------------------------------------------------------------

__global__ void k_cast(const float* __restrict__ x, ushort* __restrict__ xbf, int n4) {
    int i = blockIdx.x * blockDim.x + threadIdx.x;
    if (i < n4) {
        float4 f = ((const float4*)x)[i];
        ushort4 o; o.x = f2bf(f.x); o.y = f2bf(f.y); o.z = f2bf(f.z); o.w = f2bf(f.w);
        ((ushort4*)xbf)[i] = o;
    }
}

// ---- gate: alph = clip(sigmoid(W2 @ clip(W1 @ x + b1) + b2)) --------------
// one wave per node; lane h holds W1 row h in 128 VGPRs; x broadcast by shfl.

__global__ __launch_bounds__(256) void k_gate(const float* __restrict__ x,
                                              const float* __restrict__ W1,
                                              const float* __restrict__ b1,
                                              const float* __restrict__ W2,
                                              const float* __restrict__ b2,
                                              float* __restrict__ alph, int N) {
    int gid = blockIdx.x * blockDim.x + threadIdx.x;
    int wid = gid >> 6, lane = threadIdx.x & 63;
    int nw = (gridDim.x * blockDim.x) >> 6;
    float w[128];
#pragma unroll
    for (int j = 0; j < 32; j++) {
        float4 t = ((const float4*)(W1 + lane * 128))[j];
        w[4 * j] = t.x; w[4 * j + 1] = t.y; w[4 * j + 2] = t.z; w[4 * j + 3] = t.w;
    }
    float b1l = b1[lane], w2l = W2[lane], b2s = b2[0];
    for (int n = wid; n < N; n += nw) {
        float xa = x[(size_t)n * 128 + lane];
        float xb = x[(size_t)n * 128 + 64 + lane];
        float acc = b1l;
#pragma unroll
        for (int k = 0; k < 64; k++) acc = fmaf(__shfl(xa, k), w[k], acc);
#pragma unroll
        for (int k = 0; k < 64; k++) acc = fmaf(__shfl(xb, k), w[64 + k], acc);
        acc = fminf(fmaxf(acc, -10.f), 10.f);
        float p = acc * w2l;
#pragma unroll
        for (int off = 32; off > 0; off >>= 1) p += __shfl_xor(p, off);
        float a = 1.f / (1.f + __expf(-(p + b2s)));
        a = fminf(fmaxf(a, 1e-6f), 1.f - 1e-6f);
        if (lane == 0) alph[n] = a;
    }
}

// ---- SpMM: one wave per row, lane covers 2 of 128 columns -----------------

__global__ __launch_bounds__(256) void k_spmm1(const int* __restrict__ offs, const int* __restrict__ cnts,
                                               const int* __restrict__ col_s, const float* __restrict__ val_s,
                                               const ushort* __restrict__ xbf, ushort* __restrict__ axbf, int N) {
    int w = (blockIdx.x * blockDim.x + threadIdx.x) >> 6;
    int lane = threadIdx.x & 63;
    if (w >= N) return;
    int beg = __builtin_amdgcn_readfirstlane(offs[w]);
    int cnt = __builtin_amdgcn_readfirstlane(cnts[w]);
    float a0 = 0.f, a1 = 0.f, c0a = 0.f, c1a = 0.f;
    int e = 0;
    for (; e + 2 <= cnt; e += 2) {
        int c0 = col_s[beg + e], c1 = col_s[beg + e + 1];
        float v0 = val_s[beg + e], v1 = val_s[beg + e + 1];
        uint p0 = *(const uint*)(xbf + ((size_t)c0 * 128 + lane * 2));
        uint p1 = *(const uint*)(xbf + ((size_t)c1 * 128 + lane * 2));
        a0  = fmaf(v0, bf2f((ushort)(p0 & 0xffff)), a0);
        a1  = fmaf(v0, bf2f((ushort)(p0 >> 16)), a1);
        c0a = fmaf(v1, bf2f((ushort)(p1 & 0xffff)), c0a);
        c1a = fmaf(v1, bf2f((ushort)(p1 >> 16)), c1a);
    }
    if (e < cnt) {
        int c0 = col_s[beg + e];
        float v0 = val_s[beg + e];
        uint p0 = *(const uint*)(xbf + ((size_t)c0 * 128 + lane * 2));
        a0 = fmaf(v0, bf2f((ushort)(p0 & 0xffff)), a0);
        a1 = fmaf(v0, bf2f((ushort)(p0 >> 16)), a1);
    }
    a0 += c0a; a1 += c1a;
    uint packed = ((uint)f2bf(a1) << 16) | (uint)f2bf(a0);
    *(uint*)(axbf + ((size_t)w * 128 + lane * 2)) = packed;
}

__global__ __launch_bounds__(256) void k_spmm2(const int* __restrict__ offs, const int* __restrict__ cnts,
                                               const int* __restrict__ col_s, const float* __restrict__ val_s,
                                               const ushort* __restrict__ axbf, const float* __restrict__ alph,
                                               const float* __restrict__ x, float* __restrict__ out, int N) {
    int w = (blockIdx.x * blockDim.x + threadIdx.x) >> 6;
    int lane = threadIdx.x & 63;
    if (w >= N) return;
    int beg = __builtin_amdgcn_readfirstlane(offs[w]);
    int cnt = __builtin_amdgcn_readfirstlane(cnts[w]);
    float a0 = 0.f, a1 = 0.f, c0a = 0.f, c1a = 0.f;
    int e = 0;
    for (; e + 2 <= cnt; e += 2) {
        int c0 = col_s[beg + e], c1 = col_s[beg + e + 1];
        float v0 = val_s[beg + e], v1 = val_s[beg + e + 1];
        uint p0 = *(const uint*)(axbf + ((size_t)c0 * 128 + lane * 2));
        uint p1 = *(const uint*)(axbf + ((size_t)c1 * 128 + lane * 2));
        a0  = fmaf(v0, bf2f((ushort)(p0 & 0xffff)), a0);
        a1  = fmaf(v0, bf2f((ushort)(p0 >> 16)), a1);
        c0a = fmaf(v1, bf2f((ushort)(p1 & 0xffff)), c0a);
        c1a = fmaf(v1, bf2f((ushort)(p1 >> 16)), c1a);
    }
    if (e < cnt) {
        int c0 = col_s[beg + e];
        float v0 = val_s[beg + e];
        uint p0 = *(const uint*)(axbf + ((size_t)c0 * 128 + lane * 2));
        a0 = fmaf(v0, bf2f((ushort)(p0 & 0xffff)), a0);
        a1 = fmaf(v0, bf2f((ushort)(p0 >> 16)), a1);
    }
    a0 += c0a; a1 += c1a;
    float al = alph[w];
    float2 xr = *(const float2*)(x + (size_t)w * 128 + lane * 2);
    float2 o; o.x = fmaf(al, a0, -xr.x); o.y = fmaf(al, a1, -xr.y);
    *(float2*)(out + (size_t)w * 128 + lane * 2) = o;
}

// ---- launch ---------------------------------------------------------------

extern "C" void kernel_launch(void* const* d_in, const int* in_sizes, int n_in,
                              void* d_out, int out_size, void* d_ws, size_t ws_size,
                              hipStream_t stream) {
    const float* x   = (const float*)d_in[1];
    const int*  rows = (const int*)d_in[2];
    const int*  cols = (const int*)d_in[3];
    const float* vals = (const float*)d_in[4];
    const float* W1 = (const float*)d_in[5];
    const float* b1 = (const float*)d_in[6];
    const float* W2 = (const float*)d_in[7];
    const float* b2 = (const float*)d_in[8];
    float* out = (float*)d_out;

    int N = in_sizes[1] / 128;
    int nnz = in_sizes[2];

    char* ws = (char*)d_ws;
    size_t off = 0;
    auto take = [&](size_t bytes) -> char* {
        size_t p = (off + 255) & ~(size_t)255;
        off = p + bytes;
        return ws + p;
    };
    ushort* xbf     = (ushort*)take((size_t)N * 128 * 2);
    ushort* axbf    = (ushort*)take((size_t)N * 128 * 2);
    int*    counts  = (int*)take((size_t)N * 4);
    int*    offsets = (int*)take((size_t)N * 4);
    int*    cursor  = (int*)take((size_t)N * 4);
    float*  alph    = (float*)take((size_t)N * 4);
    int*    col_s   = (int*)take((size_t)nnz * 4);
    float*  val_s   = (float*)take((size_t)nnz * 4);
    int*    partials = (int*)take(1024 * 4);
    (void)ws_size; (void)off; (void)n_in; (void)out_size;

    int P = (N + 1023) / 1024;   // 98 for N=100000; must be <= 256

    k_zero2<<<(N + 255) / 256, 256, 0, stream>>>(counts, cursor, N);
    k_hist<<<(nnz + 255) / 256, 256, 0, stream>>>(rows, counts, nnz);
    k_scan_part<<<P, 256, 0, stream>>>(counts, partials, N);
    k_scan_root<<<1, 256, 0, stream>>>(partials, P);
    k_scan_final<<<P, 256, 0, stream>>>(counts, partials, offsets, N);
    k_scatter<<<(nnz + 255) / 256, 256, 0, stream>>>(rows, cols, vals, offsets, cursor, col_s, val_s, nnz);
    k_cast<<<((N * 32) + 255) / 256, 256, 0, stream>>>(x, xbf, N * 32);
    k_gate<<<512, 256, 0, stream>>>(x, W1, b1, W2, b2, alph, N);
    k_spmm1<<<((N * 64) + 255) / 256, 256, 0, stream>>>(offsets, counts, col_s, val_s, xbf, axbf, N);
    k_spmm2<<<((N * 64) + 255) / 256, 256, 0, stream>>>(offsets, counts, col_s, val_s, axbf, alph, x, out, N);
}

// Round 2
// 706.594 us; speedup vs baseline: 1.1678x; 1.1678x over previous
//
#include <hip/hip_runtime.h>
#include <stdint.h>

typedef unsigned int uint;
typedef unsigned short ushort;

__device__ __forceinline__ ushort f2bf(float f) {
    uint u = __float_as_uint(f);
    return (ushort)((u + 0x7fffu + ((u >> 16) & 1u)) >> 16);   // RNE
}
__device__ __forceinline__ float bf2f(ushort h) {
    return __uint_as_float(((uint)h) << 16);
}

// ---- CSR build ------------------------------------------------------------

__global__ void k_zero2(int* __restrict__ a, int* __restrict__ b, int n) {
    int i = blockIdx.x * blockDim.x + threadIdx.x;
    if (i < n) { a[i] = 0; b[i] = 0; }
}

__global__ void k_hist(const int* __restrict__ rows, int* __restrict__ counts, int nnz) {
    int i = blockIdx.x * blockDim.x + threadIdx.x;
    if (i < nnz) atomicAdd(&counts[rows[i]], 1);
}

// chunk = 1024 elements per block (256 thr * 4)
__global__ void k_scan_part(const int* __restrict__ counts, int* __restrict__ partials, int N) {
    int t = threadIdx.x;
    int base = blockIdx.x * 1024 + t * 4;
    int s = 0;
#pragma unroll
    for (int j = 0; j < 4; j++) { int idx = base + j; if (idx < N) s += counts[idx]; }
#pragma unroll
    for (int off = 32; off > 0; off >>= 1) s += __shfl_xor(s, off);
    __shared__ int wsum[4];
    int lane = t & 63, wv = t >> 6;
    if (lane == 0) wsum[wv] = s;
    __syncthreads();
    if (t == 0) partials[blockIdx.x] = wsum[0] + wsum[1] + wsum[2] + wsum[3];
}

__global__ void k_scan_root(int* partials, int P) {
    int t = threadIdx.x;
    int v = (t < P) ? partials[t] : 0;
    int lane = t & 63, wv = t >> 6;
    int inc = v;
#pragma unroll
    for (int off = 1; off < 64; off <<= 1) { int o = __shfl_up(inc, off); if (lane >= off) inc += o; }
    __shared__ int wtot[4];
    if (lane == 63) wtot[wv] = inc;
    __syncthreads();
    int woff = 0;
    for (int i = 0; i < wv; i++) woff += wtot[i];
    int excl = inc - v + woff;
    if (t < P) partials[t] = excl;
}

__global__ void k_scan_final(const int* __restrict__ counts, const int* __restrict__ partials,
                             int* __restrict__ offsets, int N) {
    int t = threadIdx.x, b = blockIdx.x;
    int base = b * 1024 + t * 4;
    int v[4]; int tsum = 0;
#pragma unroll
    for (int j = 0; j < 4; j++) { int idx = base + j; v[j] = (idx < N) ? counts[idx] : 0; tsum += v[j]; }
    int lane = t & 63, wv = t >> 6;
    int inc = tsum;
#pragma unroll
    for (int off = 1; off < 64; off <<= 1) { int o = __shfl_up(inc, off); if (lane >= off) inc += o; }
    __shared__ int wtot[4];
    if (lane == 63) wtot[wv] = inc;
    __syncthreads();
    int woff = 0;
    for (int i = 0; i < wv; i++) woff += wtot[i];
    int run = partials[b] + woff + inc - tsum;
#pragma unroll
    for (int j = 0; j < 4; j++) { int idx = base + j; if (idx < N) offsets[idx] = run; run += v[j]; }
}

// XCD-sharded scatter: shard = blockIdx & 7 (round-robin block->XCD mapping);
// shard s handles rows [s*N/8, (s+1)*N/8) so its random writes span ~3.2 MB of
// `pairs` -> stays in that XCD's 4 MB L2 until lines are fully assembled.
__global__ void k_scatter(const int* __restrict__ rows, const int* __restrict__ cols,
                          const float* __restrict__ vals, const int* __restrict__ offsets,
                          int* __restrict__ cursor, uint2* __restrict__ pairs,
                          int nnz, float inv_shard) {
    int shard = blockIdx.x & 7;
    int bIdx  = blockIdx.x >> 3;
    int nB    = gridDim.x >> 3;
    int stride = nB * blockDim.x;
    for (int i = bIdx * blockDim.x + threadIdx.x; i < nnz; i += stride) {
        int r = rows[i];
        int s = (int)((float)r * inv_shard);
        s = s > 7 ? 7 : s;
        if (s == shard) {
            int p = offsets[r] + atomicAdd(&cursor[r], 1);
            uint2 pr; pr.x = (uint)cols[i]; pr.y = __float_as_uint(vals[i]);
            pairs[p] = pr;
        }
    }
}

// ---- x -> bf16 ------------------------------------------------------------

__global__ void k_cast(const float* __restrict__ x, ushort* __restrict__ xbf, int n4) {
    int i = blockIdx.x * blockDim.x + threadIdx.x;
    if (i < n4) {
        float4 f = ((const float4*)x)[i];
        ushort4 o; o.x = f2bf(f.x); o.y = f2bf(f.y); o.z = f2bf(f.z); o.w = f2bf(f.w);
        ((ushort4*)xbf)[i] = o;
    }
}

// ---- gate: alph = clip(sigmoid(W2 @ clip(W1 @ x + b1) + b2)) --------------

__global__ __launch_bounds__(256) void k_gate(const float* __restrict__ x,
                                              const float* __restrict__ W1,
                                              const float* __restrict__ b1,
                                              const float* __restrict__ W2,
                                              const float* __restrict__ b2,
                                              float* __restrict__ alph, int N) {
    int gid = blockIdx.x * blockDim.x + threadIdx.x;
    int wid = gid >> 6, lane = threadIdx.x & 63;
    int nw = (gridDim.x * blockDim.x) >> 6;
    float w[128];
#pragma unroll
    for (int j = 0; j < 32; j++) {
        float4 t = ((const float4*)(W1 + lane * 128))[j];
        w[4 * j] = t.x; w[4 * j + 1] = t.y; w[4 * j + 2] = t.z; w[4 * j + 3] = t.w;
    }
    float b1l = b1[lane], w2l = W2[lane], b2s = b2[0];
    for (int n = wid; n < N; n += nw) {
        float xa = x[(size_t)n * 128 + lane];
        float xb = x[(size_t)n * 128 + 64 + lane];
        float acc = b1l;
#pragma unroll
        for (int k = 0; k < 64; k++) acc = fmaf(__shfl(xa, k), w[k], acc);
#pragma unroll
        for (int k = 0; k < 64; k++) acc = fmaf(__shfl(xb, k), w[64 + k], acc);
        acc = fminf(fmaxf(acc, -10.f), 10.f);
        float p = acc * w2l;
#pragma unroll
        for (int off = 32; off > 0; off >>= 1) p += __shfl_xor(p, off);
        float a = 1.f / (1.f + __expf(-(p + b2s)));
        a = fminf(fmaxf(a, 1e-6f), 1.f - 1e-6f);
        if (lane == 0) alph[n] = a;
    }
}

// ---- SpMM: one wave per row, lane covers 2 of 128 columns -----------------

__global__ __launch_bounds__(256) void k_spmm1(const int* __restrict__ offs, const int* __restrict__ cnts,
                                               const uint2* __restrict__ pairs,
                                               const ushort* __restrict__ xbf, ushort* __restrict__ axbf, int N) {
    int w = (blockIdx.x * blockDim.x + threadIdx.x) >> 6;
    int lane = threadIdx.x & 63;
    if (w >= N) return;
    int beg = __builtin_amdgcn_readfirstlane(offs[w]);
    int cnt = __builtin_amdgcn_readfirstlane(cnts[w]);
    float a0 = 0.f, a1 = 0.f, c0a = 0.f, c1a = 0.f;
    int e = 0;
    for (; e + 2 <= cnt; e += 2) {
        uint2 q0 = pairs[beg + e], q1 = pairs[beg + e + 1];
        int c0 = (int)q0.x, c1 = (int)q1.x;
        float v0 = __uint_as_float(q0.y), v1 = __uint_as_float(q1.y);
        uint p0 = *(const uint*)(xbf + ((size_t)c0 * 128 + lane * 2));
        uint p1 = *(const uint*)(xbf + ((size_t)c1 * 128 + lane * 2));
        a0  = fmaf(v0, bf2f((ushort)(p0 & 0xffff)), a0);
        a1  = fmaf(v0, bf2f((ushort)(p0 >> 16)), a1);
        c0a = fmaf(v1, bf2f((ushort)(p1 & 0xffff)), c0a);
        c1a = fmaf(v1, bf2f((ushort)(p1 >> 16)), c1a);
    }
    if (e < cnt) {
        uint2 q0 = pairs[beg + e];
        int c0 = (int)q0.x;
        float v0 = __uint_as_float(q0.y);
        uint p0 = *(const uint*)(xbf + ((size_t)c0 * 128 + lane * 2));
        a0 = fmaf(v0, bf2f((ushort)(p0 & 0xffff)), a0);
        a1 = fmaf(v0, bf2f((ushort)(p0 >> 16)), a1);
    }
    a0 += c0a; a1 += c1a;
    uint packed = ((uint)f2bf(a1) << 16) | (uint)f2bf(a0);
    *(uint*)(axbf + ((size_t)w * 128 + lane * 2)) = packed;
}

__global__ __launch_bounds__(256) void k_spmm2(const int* __restrict__ offs, const int* __restrict__ cnts,
                                               const uint2* __restrict__ pairs,
                                               const ushort* __restrict__ axbf, const float* __restrict__ alph,
                                               const float* __restrict__ x, float* __restrict__ out, int N) {
    int w = (blockIdx.x * blockDim.x + threadIdx.x) >> 6;
    int lane = threadIdx.x & 63;
    if (w >= N) return;
    int beg = __builtin_amdgcn_readfirstlane(offs[w]);
    int cnt = __builtin_amdgcn_readfirstlane(cnts[w]);
    float a0 = 0.f, a1 = 0.f, c0a = 0.f, c1a = 0.f;
    int e = 0;
    for (; e + 2 <= cnt; e += 2) {
        uint2 q0 = pairs[beg + e], q1 = pairs[beg + e + 1];
        int c0 = (int)q0.x, c1 = (int)q1.x;
        float v0 = __uint_as_float(q0.y), v1 = __uint_as_float(q1.y);
        uint p0 = *(const uint*)(axbf + ((size_t)c0 * 128 + lane * 2));
        uint p1 = *(const uint*)(axbf + ((size_t)c1 * 128 + lane * 2));
        a0  = fmaf(v0, bf2f((ushort)(p0 & 0xffff)), a0);
        a1  = fmaf(v0, bf2f((ushort)(p0 >> 16)), a1);
        c0a = fmaf(v1, bf2f((ushort)(p1 & 0xffff)), c0a);
        c1a = fmaf(v1, bf2f((ushort)(p1 >> 16)), c1a);
    }
    if (e < cnt) {
        uint2 q0 = pairs[beg + e];
        int c0 = (int)q0.x;
        float v0 = __uint_as_float(q0.y);
        uint p0 = *(const uint*)(axbf + ((size_t)c0 * 128 + lane * 2));
        a0 = fmaf(v0, bf2f((ushort)(p0 & 0xffff)), a0);
        a1 = fmaf(v0, bf2f((ushort)(p0 >> 16)), a1);
    }
    a0 += c0a; a1 += c1a;
    float al = alph[w];
    float2 xr = *(const float2*)(x + (size_t)w * 128 + lane * 2);
    float2 o; o.x = fmaf(al, a0, -xr.x); o.y = fmaf(al, a1, -xr.y);
    *(float2*)(out + (size_t)w * 128 + lane * 2) = o;
}

// ---- launch ---------------------------------------------------------------

extern "C" void kernel_launch(void* const* d_in, const int* in_sizes, int n_in,
                              void* d_out, int out_size, void* d_ws, size_t ws_size,
                              hipStream_t stream) {
    const float* x   = (const float*)d_in[1];
    const int*  rows = (const int*)d_in[2];
    const int*  cols = (const int*)d_in[3];
    const float* vals = (const float*)d_in[4];
    const float* W1 = (const float*)d_in[5];
    const float* b1 = (const float*)d_in[6];
    const float* W2 = (const float*)d_in[7];
    const float* b2 = (const float*)d_in[8];
    float* out = (float*)d_out;

    int N = in_sizes[1] / 128;
    int nnz = in_sizes[2];

    char* ws = (char*)d_ws;
    size_t off = 0;
    auto take = [&](size_t bytes) -> char* {
        size_t p = (off + 255) & ~(size_t)255;
        off = p + bytes;
        return ws + p;
    };
    ushort* xbf     = (ushort*)take((size_t)N * 128 * 2);
    ushort* axbf    = (ushort*)take((size_t)N * 128 * 2);
    int*    counts  = (int*)take((size_t)N * 4);
    int*    offsets = (int*)take((size_t)N * 4);
    int*    cursor  = (int*)take((size_t)N * 4);
    float*  alph    = (float*)take((size_t)N * 4);
    uint2*  pairs   = (uint2*)take((size_t)nnz * 8);
    int*    partials = (int*)take(1024 * 4);
    (void)ws_size; (void)off; (void)n_in; (void)out_size;

    int P = (N + 1023) / 1024;   // 98 for N=100000; must be <= 256
    float inv_shard = 8.0f / (float)N;

    k_zero2<<<(N + 255) / 256, 256, 0, stream>>>(counts, cursor, N);
    k_hist<<<(nnz + 255) / 256, 256, 0, stream>>>(rows, counts, nnz);
    k_scan_part<<<P, 256, 0, stream>>>(counts, partials, N);
    k_scan_root<<<1, 256, 0, stream>>>(partials, P);
    k_scan_final<<<P, 256, 0, stream>>>(counts, partials, offsets, N);
    k_scatter<<<8 * 128, 256, 0, stream>>>(rows, cols, vals, offsets, cursor, pairs, nnz, inv_shard);
    k_cast<<<((N * 32) + 255) / 256, 256, 0, stream>>>(x, xbf, N * 32);
    k_gate<<<512, 256, 0, stream>>>(x, W1, b1, W2, b2, alph, N);
    k_spmm1<<<((N * 64) + 255) / 256, 256, 0, stream>>>(offsets, counts, pairs, xbf, axbf, N);
    k_spmm2<<<((N * 64) + 255) / 256, 256, 0, stream>>>(offsets, counts, pairs, axbf, alph, x, out, N);
}